// Round 2
// baseline (70.813 us; speedup 1.0000x reference)
//
#include <hip/hip_runtime.h>
#include <cstdint>
#include <cstddef>

// out[b,l] = min_d max(x[b,d], 1 - clip(w[l,d],0,1)),  B=1024, L=512, D=512, f32.
//
// R8: single kernel node (R7 post-mortem: two very different kernel structures
// measured identically -> dur is dominated by harness fixed cost; the only
// remaining lever is node count + kernel work). Structure:
//  - Full-D 32x32 tile per block, 64 KB LDS (two 32x512 fp16 planes),
//    __launch_bounds__(512,4) -> 2 blocks/CU, 512 blocks = exactly resident.
//  - In-kernel f32->fp16 convert, ONCE per block, reg-staged:
//    waves 0-3 stage x rows, waves 4-7 stage c=1-clip(w) rows.
//    Swizzle on the GLOBAL chunk index (lane fetches chunk (p-rs-h)&7),
//    LDS writes stay LINEAR (lane*16B, floor-cost ds_write_b128).
//  - Compute: wave w owns d-window [w*64,w*64+64), no barriers; read rotation
//    ((c+bg+wave)&7 / (c+lg+wave)&7) undoes the staging swizzle -> 8 distinct
//    bank-quads per ds_read_b128 (conflict-free), both operands aligned on the
//    same global d-chunk.
//  - Flat one-shot cross-wave reduction (stride-72 pad, 2-way aliasing = free).

typedef _Float16 h2 __attribute__((ext_vector_type(2)));
typedef _Float16 h4 __attribute__((ext_vector_type(4)));
typedef _Float16 h8 __attribute__((ext_vector_type(8)));
typedef __fp16   fp16x2 __attribute__((ext_vector_type(2)));  // cvt_pkrtz return type

constexpr int Dv = 512;
constexpr int Lv = 512;
constexpr int Bv = 1024;

static __device__ __forceinline__ h8 max8(h8 a, h8 b) { return __builtin_elementwise_max(a, b); }
static __device__ __forceinline__ h4 min4(h4 a, h4 b) { return __builtin_elementwise_min(a, b); }
static __device__ __forceinline__ h2 min2(h2 a, h2 b) { return __builtin_elementwise_min(a, b); }

static __device__ __forceinline__ h2 pkrtz(float a, float b) {
  fp16x2 r = __builtin_amdgcn_cvt_pkrtz(a, b);
  return __builtin_bit_cast(h2, r);
}

static __device__ __forceinline__ float clip01_inv(float v) {
  return 1.f - fminf(fmaxf(v, 0.f), 1.f);  // folds to v_med3 + v_sub
}

__global__ __launch_bounds__(512, 4) void softand_fused(
    const float* __restrict__ x, const float* __restrict__ w,
    float* __restrict__ out)
{
  // Two 32x512 fp16 planes: full-D tiles, 32 KB each -> 64 KB total.
  __shared__ _Float16 smem[2 * 32 * Dv] __attribute__((aligned(16)));
  _Float16* xs = smem;
  _Float16* cs = smem + 32 * Dv;

  const int t    = threadIdx.x;
  const int wave = t >> 6;
  const int lane = t & 63;
  const int bx   = blockIdx.x >> 4;   // [0,32) b-tile
  const int by   = blockIdx.x & 15;   // [0,16) l-tile
  const int b0 = bx * 32, l0 = by * 32;

  const int bg = lane >> 3;   // [0,8) b-group (rows bg*4..bg*4+3)
  const int lg = lane & 7;    // [0,8) l-group (rows rl..rl+3)
  const int rb = bg * 4;
  const int rl = lg * 4;

  // ---- Stage + convert, once per block. Waves 0-3: x rows (8 each);
  // waves 4-7: c rows. Per row, lane covers one 16B fp16 chunk (8 d):
  // window h = lane>>3, linear slot p = lane&7. Content rule so that the
  // compute read rotation recovers global chunk c:
  //   content(slot p, window h, row r) = global chunk (p - (r>>2) - h) & 7.
  // Global loads stay segment-covering (permutation of 32B chunks within each
  // 256B window); LDS writes are contiguous (lane*16B -> floor cost).
  {
    const int h = lane >> 3;        // d-window [0,8)
    const int p = lane & 7;         // linear chunk slot within window
    const bool isx = wave < 4;
    const int wv = isx ? wave : wave - 4;
    const float* src = isx ? (x + (size_t)b0 * Dv) : (w + (size_t)l0 * Dv);
    _Float16* dst = isx ? xs : cs;
    #pragma unroll
    for (int k = 0; k < 8; ++k) {
      const int r  = wv * 8 + k;                 // row within tile [0,32)
      const int rs = (r >> 2) & 7;
      const int g  = (p - rs - h) & 7;           // global chunk to fetch
      const float* gp = src + (size_t)r * Dv + h * 64 + g * 8;
      const float4 a = *(const float4*)gp;
      const float4 b = *(const float4*)(gp + 4);
      h2 q0, q1, q2, q3;
      if (isx) {
        q0 = pkrtz(a.x, a.y); q1 = pkrtz(a.z, a.w);
        q2 = pkrtz(b.x, b.y); q3 = pkrtz(b.z, b.w);
      } else {
        q0 = pkrtz(clip01_inv(a.x), clip01_inv(a.y));
        q1 = pkrtz(clip01_inv(a.z), clip01_inv(a.w));
        q2 = pkrtz(clip01_inv(b.x), clip01_inv(b.y));
        q3 = pkrtz(clip01_inv(b.z), clip01_inv(b.w));
      }
      *(h8*)(dst + r * Dv + lane * 8) =
          h8{q0.x, q0.y, q1.x, q1.y, q2.x, q2.y, q3.x, q3.y};
    }
  }
  __syncthreads();

  // ---- Compute: wave w owns d-window [w*64, w*64+64), no barriers.
  const h2 hinit = h2{(_Float16)65504.f, (_Float16)65504.f};
  h2 acc[16];
  #pragma unroll
  for (int o = 0; o < 16; ++o) acc[o] = hinit;

  const _Float16* xw = xs + rb * Dv + wave * 64;
  const _Float16* cw = cs + rl * Dv + wave * 64;

  #pragma unroll
  for (int c = 0; c < 8; ++c) {
    h8 xv[4], cv[4];
    const int ox = ((c + bg + wave) & 7) * 8;
    const int oc = ((c + lg + wave) & 7) * 8;
    #pragma unroll
    for (int i = 0; i < 4; ++i) xv[i] = *(const h8*)(xw + i * Dv + ox);
    #pragma unroll
    for (int j = 0; j < 4; ++j) cv[j] = *(const h8*)(cw + j * Dv + oc);
    #pragma unroll
    for (int i = 0; i < 4; ++i) {
      #pragma unroll
      for (int j = 0; j < 4; ++j) {
        const h8 t8 = max8(xv[i], cv[j]);
        const h4 lo4 = __builtin_shufflevector(t8, t8, 0, 1, 2, 3);
        const h4 hi4 = __builtin_shufflevector(t8, t8, 4, 5, 6, 7);
        const h4 m4  = min4(lo4, hi4);
        const h2 l2  = __builtin_shufflevector(m4, m4, 0, 1);
        const h2 h2v = __builtin_shufflevector(m4, m4, 2, 3);
        acc[i * 4 + j] = min2(acc[i * 4 + j], min2(l2, h2v));
      }
    }
  }

  // Fold d-pairs -> fin[i*2+jp] = (row rb+i, cols rl+jp*2, +1)
  h2 fin[8];
  #pragma unroll
  for (int i = 0; i < 4; ++i) {
    #pragma unroll
    for (int jp = 0; jp < 2; ++jp) {
      const h2 a0 = acc[i * 4 + jp * 2];
      const h2 a1 = acc[i * 4 + jp * 2 + 1];
      const _Float16 m0 = a0.x < a0.y ? a0.x : a0.y;
      const _Float16 m1 = a1.x < a1.y ? a1.x : a1.y;
      fin[i * 2 + jp] = h2{m0, m1};
    }
  }

  // ---- Flat cross-wave reduction: one LDS round trip, 2 barriers total.
  // red[(w*8+k)*72 + lane]; stride 72 => banks (k*8+lane)&31: worst 2-way (free).
  __syncthreads();  // everyone done reading xs/cs before overlay
  h2* red = (h2*)smem;
  #pragma unroll
  for (int k = 0; k < 8; ++k) red[(wave * 8 + k) * 72 + lane] = fin[k];
  __syncthreads();

  // Each of the 512 threads min-reduces its output pair across the 8 waves.
  {
    const int b_loc = t >> 4;       // [0,32)
    const int lp    = t & 15;       // h2-column within tile
    const int kk    = (b_loc & 3) * 2 + (lp & 1);
    const int ls    = (b_loc >> 2) * 8 + (lp >> 1);
    h2 v = red[kk * 72 + ls];
    #pragma unroll
    for (int w8 = 1; w8 < 8; ++w8) v = min2(v, red[(w8 * 8 + kk) * 72 + ls]);
    float2 o;
    o.x = (float)v.x;
    o.y = (float)v.y;
    *(float2*)(out + (size_t)(b0 + b_loc) * Lv + l0 + lp * 2) = o;
  }
}

extern "C" void kernel_launch(void* const* d_in, const int* in_sizes, int n_in,
                              void* d_out, int out_size, void* d_ws, size_t ws_size,
                              hipStream_t stream) {
  const float* x = (const float*)d_in[0];
  const float* w = (const float*)d_in[1];
  float* out = (float*)d_out;
  (void)d_ws; (void)ws_size; (void)in_sizes; (void)n_in; (void)out_size;

  softand_fused<<<512, 512, 0, stream>>>(x, w, out);
}